// Round 7
// baseline (198.920 us; speedup 1.0000x reference)
//
#include <hip/hip_runtime.h>
#include <math.h>

// Problem constants
#define N_ROWS 100000
#define IN_C   256
#define OUT_C  128
#define NHEAD  4
#define NCLS   1000
#define NCOPY  16      // privatization factor for histogram/buckets
#define CAP    64      // bucket capacity per (copy,class); lambda=6.25, ~10-sigma margin
#define RPB    32      // rows per k_score block (4 waves x 8 iters)

// Workspace layout (float/uint elements); ~5.14M elems = 20.5 MB
#define OFF_V      0          // 1024: folded V[4][256]
#define OFF_CB     1024       // 4:    folded bias c[4]
#define OFF_CNT    1032       // NCOPY*NCLS = 16000 privatized counters
#define OFF_BUCKET 17032      // NCOPY*NCLS*CAP = 1,024,000 row-id buckets
#define OFF_PB     1041032    // NCOPY*NCLS*CAP float4: p per bucket slot

// ---- K1: fused counter zero + weight folding ----
__global__ __launch_bounds__(256) void k_prep(const float* __restrict__ W_lin,
                                              const float* __restrict__ b_lin,
                                              const float* __restrict__ W_att,
                                              const float* __restrict__ b_att,
                                              float* __restrict__ ws) {
    const int b = blockIdx.x, t = threadIdx.x;
    if (b >= NHEAD) {
        int i = (b - NHEAD) * 256 + t;   // 63*256 = 16128 >= 16000
        if (i < NCOPY * NCLS) ((unsigned*)(ws + OFF_CNT))[i] = 0u;
        return;
    }
    __shared__ float sw[OUT_C];
    __shared__ float rb[256];
    if (t < OUT_C) sw[t] = W_att[t];
    __syncthreads();
    const float* wl = W_lin + (size_t)(b * OUT_C) * IN_C + t;
    float s0 = 0.f, s1 = 0.f, s2 = 0.f, s3 = 0.f;
    #pragma unroll 8
    for (int o = 0; o < OUT_C; o += 4) {
        s0 = fmaf(wl[(size_t)(o + 0) * IN_C], sw[o + 0], s0);
        s1 = fmaf(wl[(size_t)(o + 1) * IN_C], sw[o + 1], s1);
        s2 = fmaf(wl[(size_t)(o + 2) * IN_C], sw[o + 2], s2);
        s3 = fmaf(wl[(size_t)(o + 3) * IN_C], sw[o + 3], s3);
    }
    (ws + OFF_V)[b * IN_C + t] = (s0 + s1) + (s2 + s3);
    rb[t] = (t < OUT_C) ? b_lin[b * OUT_C + t] * sw[t] : 0.f;
    __syncthreads();
    for (int d = 128; d; d >>= 1) {
        if (t < d) rb[t] += rb[t + d];
        __syncthreads();
    }
    if (t == 0) (ws + OFF_CB)[b] = rb[0] + b_att[0];
}

// ---- K2: scores -> p = exp(leaky(score)) into buckets; 1-ahead load pipeline ----
__global__ __launch_bounds__(256) void k_score(const float* __restrict__ ch,
                                               const int* __restrict__ y,
                                               float* __restrict__ ws) {
    const int t = threadIdx.x;
    const int wave = t >> 6, lane = t & 63;
    const float4* V4 = (const float4*)(ws + OFF_V);
    float4 v0 = V4[0 * 64 + lane];
    float4 v1 = V4[1 * 64 + lane];
    float4 v2 = V4[2 * 64 + lane];
    float4 v3 = V4[3 * 64 + lane];
    float4 cbv = *(const float4*)(ws + OFF_CB);
    float cb = (lane & 1) ? ((lane & 2) ? cbv.w : cbv.y)
                          : ((lane & 2) ? cbv.z : cbv.x);   // lanes 0..3 -> heads 0..3
    const unsigned copyBase = (blockIdx.x & (NCOPY - 1)) * NCLS;
    unsigned* cnt     = (unsigned*)(ws + OFF_CNT);
    unsigned* bucket  = (unsigned*)(ws + OFF_BUCKET);
    float4*   pbucket = (float4*)(ws + OFF_PB);
    const int base = blockIdx.x * RPB + wave;  // 3125 * 32 == 100000, no tail
    const float4* ch4 = (const float4*)ch;

    float4 x = ch4[(size_t)base * 64 + lane];  // prologue load (it=0)
    #pragma unroll
    for (int it = 0; it < RPB / 4; ++it) {
        const int n = base + it * 4;
        // issue next iteration's load before the dependent reduce chain
        float4 xn = x;
        if (it < RPB / 4 - 1) xn = ch4[(size_t)(n + 4) * 64 + lane];
        float p0 = x.x * v0.x + x.y * v0.y + x.z * v0.z + x.w * v0.w;
        float p1 = x.x * v1.x + x.y * v1.y + x.z * v1.z + x.w * v1.w;
        float p2 = x.x * v2.x + x.y * v2.y + x.z * v2.z + x.w * v2.w;
        float p3 = x.x * v3.x + x.y * v3.y + x.z * v3.z + x.w * v3.w;
        // 4x4 transpose-reduce within quads (3 shuffles), then tree (4)
        float a01 = (lane & 1) ? p1 : p0;
        float b01 = (lane & 1) ? p0 : p1;
        b01 = __shfl_xor(b01, 1);  a01 += b01;
        float a23 = (lane & 1) ? p3 : p2;
        float b23 = (lane & 1) ? p2 : p3;
        b23 = __shfl_xor(b23, 1);  a23 += b23;
        float e = (lane & 2) ? a23 : a01;
        float f = (lane & 2) ? a01 : a23;
        f = __shfl_xor(f, 2);      e += f;
        e += __shfl_down(e, 4);
        e += __shfl_down(e, 8);
        e += __shfl_down(e, 16);
        e += __shfl_down(e, 32);
        // lanes 0..3 hold heads 0..3; |score| <~ 3 so exp(score) is fp32-safe
        float s = e + cb;
        s = s >= 0.0f ? s : 0.2f * s;          // leaky_relu(0.2)
        float p = expf(s);                     // garbage in lanes >=4, unused
        float h0 = __shfl(p, 0), h1 = __shfl(p, 1);
        float h2 = __shfl(p, 2), h3 = __shfl(p, 3);
        if (lane == 0) {
            unsigned idx = copyBase + (unsigned)y[n];
            unsigned pos = atomicAdd(&cnt[idx], 1u);   // avg 6.25 adds/address
            if (pos < CAP) {
                bucket[idx * CAP + pos]  = (unsigned)n;
                pbucket[idx * CAP + pos] = make_float4(h0, h1, h2, h3);
            }
        }
        x = xn;
    }
}

// ---- K3: per-class pooling: compact (ids + p) to LDS -> x-gather accumulate ----
__global__ __launch_bounds__(512) void k_pool(const float* __restrict__ ch,
                                              float* __restrict__ out,
                                              const float* __restrict__ ws) {
    __shared__ unsigned rowbuf[NCOPY * CAP];   // 1024 ids (4 KB)
    __shared__ float4   pbuf[NCOPY * CAP];     // 1024 p-vectors (16 KB)
    __shared__ float4   sAcc[NHEAD][4][64];    // paired-wave partials (16 KB)
    const int c = blockIdx.x, t = threadIdx.x;
    const int wave = t >> 6, lane = t & 63;
    const unsigned* cntA    = (const unsigned*)(ws + OFF_CNT);
    const unsigned* bucket  = (const unsigned*)(ws + OFF_BUCKET);
    const float4*   pbucket = (const float4*)(ws + OFF_PB);
    float* o = out + (size_t)c * (NHEAD * IN_C);

    // Per-copy counts (uniform) + exclusive prefix + total
    unsigned cc[NCOPY], pre[NCOPY];
    unsigned cnt = 0;
    #pragma unroll
    for (int cp = 0; cp < NCOPY; ++cp) {
        unsigned v = cntA[cp * NCLS + c];
        cc[cp] = v > CAP ? CAP : v;
        pre[cp] = cnt;
        cnt += cc[cp];
    }
    if (cnt == 0) {  // empty segment -> zeros
        if (t < 256) ((float4*)o)[t] = make_float4(0.f, 0.f, 0.f, 0.f);
        return;
    }
    // Parallel compaction of the 16 bucket slices (ids + p) into LDS
    for (int tt = t; tt < NCOPY * CAP; tt += 512) {
        int cp = tt >> 6, j = tt & (CAP - 1);
        if ((unsigned)j < cc[cp]) {
            unsigned src = (cp * NCLS + c) * CAP + j;
            unsigned dst = pre[cp] + j;
            rowbuf[dst] = bucket[src];
            pbuf[dst]   = pbucket[src];
        }
    }
    __syncthreads();

    const float4* ch4 = (const float4*)ch;
    const float4 z = make_float4(0.f, 0.f, 0.f, 0.f);

    // Wave w handles row pairs {2w,2w+1} + 16k; lane owns channels 4*lane..4*lane+3.
    // p comes from LDS; x gathers pipelined TWO pairs ahead (6 rows in flight/wave).
    float4 a0 = z, a1 = z, a2 = z, a3 = z;
    {
        unsigned r = 2 * (unsigned)wave;
        float4 xA0 = z, xA1 = z, xB0 = z, xB1 = z;
        if (r < cnt)          xA0 = ch4[(size_t)rowbuf[r] * 64 + lane];
        if (r + 1 < cnt)      xA1 = ch4[(size_t)rowbuf[r + 1] * 64 + lane];
        if (r + 16 < cnt)     xB0 = ch4[(size_t)rowbuf[r + 16] * 64 + lane];
        if (r + 17 < cnt)     xB1 = ch4[(size_t)rowbuf[r + 17] * 64 + lane];
        for (; r < cnt; r += 16) {
            unsigned rc = r + 32;
            float4 xC0 = z, xC1 = z;
            if (rc < cnt)     xC0 = ch4[(size_t)rowbuf[rc] * 64 + lane];
            if (rc + 1 < cnt) xC1 = ch4[(size_t)rowbuf[rc + 1] * 64 + lane];
            float4 p0 = pbuf[r];                              // LDS broadcast
            float4 p1 = (r + 1 < cnt) ? pbuf[r + 1] : z;
            a0.x = fmaf(xA0.x, p0.x, a0.x); a0.y = fmaf(xA0.y, p0.x, a0.y);
            a0.z = fmaf(xA0.z, p0.x, a0.z); a0.w = fmaf(xA0.w, p0.x, a0.w);
            a1.x = fmaf(xA0.x, p0.y, a1.x); a1.y = fmaf(xA0.y, p0.y, a1.y);
            a1.z = fmaf(xA0.z, p0.y, a1.z); a1.w = fmaf(xA0.w, p0.y, a1.w);
            a2.x = fmaf(xA0.x, p0.z, a2.x); a2.y = fmaf(xA0.y, p0.z, a2.y);
            a2.z = fmaf(xA0.z, p0.z, a2.z); a2.w = fmaf(xA0.w, p0.z, a2.w);
            a3.x = fmaf(xA0.x, p0.w, a3.x); a3.y = fmaf(xA0.y, p0.w, a3.y);
            a3.z = fmaf(xA0.z, p0.w, a3.z); a3.w = fmaf(xA0.w, p0.w, a3.w);
            a0.x = fmaf(xA1.x, p1.x, a0.x); a0.y = fmaf(xA1.y, p1.x, a0.y);
            a0.z = fmaf(xA1.z, p1.x, a0.z); a0.w = fmaf(xA1.w, p1.x, a0.w);
            a1.x = fmaf(xA1.x, p1.y, a1.x); a1.y = fmaf(xA1.y, p1.y, a1.y);
            a1.z = fmaf(xA1.z, p1.y, a1.z); a1.w = fmaf(xA1.w, p1.y, a1.w);
            a2.x = fmaf(xA1.x, p1.z, a2.x); a2.y = fmaf(xA1.y, p1.z, a2.y);
            a2.z = fmaf(xA1.z, p1.z, a2.z); a2.w = fmaf(xA1.w, p1.z, a2.w);
            a3.x = fmaf(xA1.x, p1.w, a3.x); a3.y = fmaf(xA1.y, p1.w, a3.y);
            a3.z = fmaf(xA1.z, p1.w, a3.z); a3.w = fmaf(xA1.w, p1.w, a3.w);
            xA0 = xB0; xA1 = xB1; xB0 = xC0; xB1 = xC1;
        }
    }
    // Paired-wave pre-reduction: waves 0-3 store, waves 4-7 add in place
    if (wave < 4) {
        sAcc[0][wave][lane] = a0; sAcc[1][wave][lane] = a1;
        sAcc[2][wave][lane] = a2; sAcc[3][wave][lane] = a3;
    }
    __syncthreads();
    if (wave >= 4) {
        int w = wave - 4;
        float4 q;
        q = sAcc[0][w][lane]; q.x += a0.x; q.y += a0.y; q.z += a0.z; q.w += a0.w; sAcc[0][w][lane] = q;
        q = sAcc[1][w][lane]; q.x += a1.x; q.y += a1.y; q.z += a1.z; q.w += a1.w; sAcc[1][w][lane] = q;
        q = sAcc[2][w][lane]; q.x += a2.x; q.y += a2.y; q.z += a2.z; q.w += a2.w; sAcc[2][w][lane] = q;
        q = sAcc[3][w][lane]; q.x += a3.x; q.y += a3.y; q.z += a3.z; q.w += a3.w; sAcc[3][w][lane] = q;
    }
    __syncthreads();

    // Epilogue: wave h (h<4) reduces head h; denominator from LDS pbuf (lane-distinct)
    if (wave < NHEAD) {
        float4 q0 = sAcc[wave][0][lane], q1 = sAcc[wave][1][lane],
               q2 = sAcc[wave][2][lane], q3 = sAcc[wave][3][lane];
        float4 acc = make_float4((q0.x + q1.x) + (q2.x + q3.x),
                                 (q0.y + q1.y) + (q2.y + q3.y),
                                 (q0.z + q1.z) + (q2.z + q3.z),
                                 (q0.w + q1.w) + (q2.w + q3.w));
        float dh = 0.f;
        for (unsigned rr = lane; rr < cnt; rr += 64) {
            float4 pp = pbuf[rr];
            dh += (wave == 0) ? pp.x : (wave == 1) ? pp.y : (wave == 2) ? pp.z : pp.w;
        }
        #pragma unroll
        for (int d = 1; d < 64; d <<= 1) dh += __shfl_xor(dh, d);
        float inv = 1.0f / dh;
        ((float4*)o)[wave * 64 + lane] =
            make_float4(acc.x * inv, acc.y * inv, acc.z * inv, acc.w * inv);
    }
}

extern "C" void kernel_launch(void* const* d_in, const int* in_sizes, int n_in,
                              void* d_out, int out_size, void* d_ws, size_t ws_size,
                              hipStream_t stream) {
    const float* ch    = (const float*)d_in[0];
    const float* W_lin = (const float*)d_in[1];
    const float* b_lin = (const float*)d_in[2];
    const float* W_att = (const float*)d_in[3];
    const float* b_att = (const float*)d_in[4];
    const int*   y     = (const int*)d_in[5];
    float* out = (float*)d_out;
    float* ws  = (float*)d_ws;  // ~20.5 MB used

    k_prep <<<NHEAD + 63, 256, 0, stream>>>(W_lin, b_lin, W_att, b_att, ws);
    k_score<<<N_ROWS / RPB, 256, 0, stream>>>(ch, y, ws);
    k_pool <<<NCLS, 512, 0, stream>>>(ch, out, ws);
}

// Round 8
// 184.717 us; speedup vs baseline: 1.0769x; 1.0769x over previous
//
#include <hip/hip_runtime.h>
#include <math.h>

// Problem constants
#define N_ROWS 100000
#define IN_C   256
#define OUT_C  128
#define NHEAD  4
#define NCLS   1000
#define NCOPY  16      // privatization factor for histogram/buckets
#define CAP    64      // bucket capacity per (copy,class); lambda=6.25, ~10-sigma margin

// Workspace layout (float/uint elements); ~1.04M elems = 4.2 MB
#define OFF_V      0          // 1024: folded V[4][256]
#define OFF_CB     1024       // 4:    folded bias c[4]
#define OFF_CNT    1032       // NCOPY*NCLS = 16000 privatized counters
#define OFF_BUCKET 17032      // NCOPY*NCLS*CAP = 1,024,000 row-id buckets

// ---- K1: fused counter zero + weight folding ----
__global__ __launch_bounds__(256) void k_prep(const float* __restrict__ W_lin,
                                              const float* __restrict__ b_lin,
                                              const float* __restrict__ W_att,
                                              const float* __restrict__ b_att,
                                              float* __restrict__ ws) {
    const int b = blockIdx.x, t = threadIdx.x;
    if (b >= NHEAD) {
        int i = (b - NHEAD) * 256 + t;   // 63*256 = 16128 >= 16000
        if (i < NCOPY * NCLS) ((unsigned*)(ws + OFF_CNT))[i] = 0u;
        return;
    }
    __shared__ float sw[OUT_C];
    __shared__ float rb[256];
    if (t < OUT_C) sw[t] = W_att[t];
    __syncthreads();
    const float* wl = W_lin + (size_t)(b * OUT_C) * IN_C + t;
    float s0 = 0.f, s1 = 0.f, s2 = 0.f, s3 = 0.f;
    #pragma unroll 8
    for (int o = 0; o < OUT_C; o += 4) {
        s0 = fmaf(wl[(size_t)(o + 0) * IN_C], sw[o + 0], s0);
        s1 = fmaf(wl[(size_t)(o + 1) * IN_C], sw[o + 1], s1);
        s2 = fmaf(wl[(size_t)(o + 2) * IN_C], sw[o + 2], s2);
        s3 = fmaf(wl[(size_t)(o + 3) * IN_C], sw[o + 3], s3);
    }
    (ws + OFF_V)[b * IN_C + t] = (s0 + s1) + (s2 + s3);
    rb[t] = (t < OUT_C) ? b_lin[b * OUT_C + t] * sw[t] : 0.f;
    __syncthreads();
    for (int d = 128; d; d >>= 1) {
        if (t < d) rb[t] += rb[t + d];
        __syncthreads();
    }
    if (t == 0) (ws + OFF_CB)[b] = rb[0] + b_att[0];
}

// ---- K2: bucket rows by class (reads ONLY y — no ch traffic) ----
__global__ __launch_bounds__(256) void k_bucket(const int* __restrict__ y,
                                                float* __restrict__ ws) {
    int n = blockIdx.x * 256 + threadIdx.x;
    if (n >= N_ROWS) return;
    unsigned* cnt    = (unsigned*)(ws + OFF_CNT);
    unsigned* bucket = (unsigned*)(ws + OFF_BUCKET);
    unsigned idx = (blockIdx.x & (NCOPY - 1)) * NCLS + (unsigned)y[n];
    unsigned pos = atomicAdd(&cnt[idx], 1u);   // ~6.25 adds/address avg
    if (pos < CAP) bucket[idx * CAP + pos] = (unsigned)n;
}

// ---- K3: single-pass pooling: compact ids -> per-row score+exp in-loop -> accumulate ----
// ch is read exactly ONCE device-wide (here); score = x.V computed from the row
// already in registers (16 FMA + 11 shuffles), so k_score's 102 MB pass is gone.
__global__ __launch_bounds__(512) void k_pool(const float* __restrict__ ch,
                                              float* __restrict__ out,
                                              const float* __restrict__ ws) {
    __shared__ unsigned rowbuf[NCOPY * CAP];   // 1024 ids (4 KB)
    __shared__ float4   sAcc[NHEAD][4][64];    // paired-wave partials (16 KB)
    __shared__ float4   sDs[8];                // per-wave denom partials
    const int c = blockIdx.x, t = threadIdx.x;
    const int wave = t >> 6, lane = t & 63;
    const unsigned* cntA   = (const unsigned*)(ws + OFF_CNT);
    const unsigned* bucket = (const unsigned*)(ws + OFF_BUCKET);
    float* o = out + (size_t)c * (NHEAD * IN_C);

    // Per-copy counts (uniform) + exclusive prefix + total
    unsigned cc[NCOPY], pre[NCOPY];
    unsigned cnt = 0;
    #pragma unroll
    for (int cp = 0; cp < NCOPY; ++cp) {
        unsigned v = cntA[cp * NCLS + c];
        cc[cp] = v > CAP ? CAP : v;
        pre[cp] = cnt;
        cnt += cc[cp];
    }
    if (cnt == 0) {  // empty segment -> zeros
        if (t < 256) ((float4*)o)[t] = make_float4(0.f, 0.f, 0.f, 0.f);
        return;
    }
    // Compact bucket id slices into LDS (2 strided iters)
    for (int tt = t; tt < NCOPY * CAP; tt += 512) {
        int cp = tt >> 6, j = tt & (CAP - 1);
        if ((unsigned)j < cc[cp])
            rowbuf[pre[cp] + j] = bucket[(cp * NCLS + c) * CAP + j];
    }
    __syncthreads();

    // Folded weights in registers (per lane: 4 channels x 4 heads)
    const float4* V4 = (const float4*)(ws + OFF_V);
    float4 v0 = V4[0 * 64 + lane];
    float4 v1 = V4[1 * 64 + lane];
    float4 v2 = V4[2 * 64 + lane];
    float4 v3 = V4[3 * 64 + lane];
    float4 cbv = *(const float4*)(ws + OFF_CB);
    float cb = (lane & 1) ? ((lane & 2) ? cbv.w : cbv.y)
                          : ((lane & 2) ? cbv.z : cbv.x);   // head = lane&3

    const float4* ch4 = (const float4*)ch;
    const float4 z = make_float4(0.f, 0.f, 0.f, 0.f);

    // Wave w: row pairs {2w,2w+1}+16k; lane owns channels 4*lane..4*lane+3.
    // x loads pipelined two pairs ahead; per row: dot -> leaky -> exp -> accumulate.
    float4 a0 = z, a1 = z, a2 = z, a3 = z, dsum = z;
    {
        unsigned r = 2 * (unsigned)wave;
        float4 xA0 = z, xA1 = z, xB0 = z, xB1 = z;
        if (r < cnt)      xA0 = ch4[(size_t)rowbuf[r] * 64 + lane];
        if (r + 1 < cnt)  xA1 = ch4[(size_t)rowbuf[r + 1] * 64 + lane];
        if (r + 16 < cnt) xB0 = ch4[(size_t)rowbuf[r + 16] * 64 + lane];
        if (r + 17 < cnt) xB1 = ch4[(size_t)rowbuf[r + 17] * 64 + lane];
        for (; r < cnt; r += 16) {
            unsigned rc = r + 32;
            float4 xC0 = z, xC1 = z;
            if (rc < cnt)     xC0 = ch4[(size_t)rowbuf[rc] * 64 + lane];
            if (rc + 1 < cnt) xC1 = ch4[(size_t)rowbuf[rc + 1] * 64 + lane];

            #pragma unroll
            for (int k = 0; k < 2; ++k) {
                const float4 x = k ? xA1 : xA0;
                const float g = k ? ((r + 1 < cnt) ? 1.f : 0.f) : 1.f;  // validity gate
                float p0 = x.x * v0.x + x.y * v0.y + x.z * v0.z + x.w * v0.w;
                float p1 = x.x * v1.x + x.y * v1.y + x.z * v1.z + x.w * v1.w;
                float p2 = x.x * v2.x + x.y * v2.y + x.z * v2.z + x.w * v2.w;
                float p3 = x.x * v3.x + x.y * v3.y + x.z * v3.z + x.w * v3.w;
                // quad transpose (3 shuffles) + full butterfly (4) -> every lane
                // holds head (lane&3)'s complete dot product
                float a01 = (lane & 1) ? p1 : p0;
                float b01 = (lane & 1) ? p0 : p1;
                b01 = __shfl_xor(b01, 1);  a01 += b01;
                float a23 = (lane & 1) ? p3 : p2;
                float b23 = (lane & 1) ? p2 : p3;
                b23 = __shfl_xor(b23, 1);  a23 += b23;
                float e = (lane & 2) ? a23 : a01;
                float f = (lane & 2) ? a01 : a23;
                f = __shfl_xor(f, 2);      e += f;
                e += __shfl_xor(e, 4);
                e += __shfl_xor(e, 8);
                e += __shfl_xor(e, 16);
                e += __shfl_xor(e, 32);
                float s = e + cb;
                s = s >= 0.0f ? s : 0.2f * s;   // leaky_relu(0.2)
                float pe = expf(s) * g;         // |s| <~ 3: shift-free exp is fp32-safe
                float h0 = __shfl(pe, 0), h1 = __shfl(pe, 1);
                float h2 = __shfl(pe, 2), h3 = __shfl(pe, 3);
                dsum.x += h0; dsum.y += h1; dsum.z += h2; dsum.w += h3;
                a0.x = fmaf(x.x, h0, a0.x); a0.y = fmaf(x.y, h0, a0.y);
                a0.z = fmaf(x.z, h0, a0.z); a0.w = fmaf(x.w, h0, a0.w);
                a1.x = fmaf(x.x, h1, a1.x); a1.y = fmaf(x.y, h1, a1.y);
                a1.z = fmaf(x.z, h1, a1.z); a1.w = fmaf(x.w, h1, a1.w);
                a2.x = fmaf(x.x, h2, a2.x); a2.y = fmaf(x.y, h2, a2.y);
                a2.z = fmaf(x.z, h2, a2.z); a2.w = fmaf(x.w, h2, a2.w);
                a3.x = fmaf(x.x, h3, a3.x); a3.y = fmaf(x.y, h3, a3.y);
                a3.z = fmaf(x.z, h3, a3.z); a3.w = fmaf(x.w, h3, a3.w);
            }
            xA0 = xB0; xA1 = xB1; xB0 = xC0; xB1 = xC1;
        }
    }
    // Paired-wave pre-reduction: waves 0-3 store, waves 4-7 add in place
    if (wave < 4) {
        sAcc[0][wave][lane] = a0; sAcc[1][wave][lane] = a1;
        sAcc[2][wave][lane] = a2; sAcc[3][wave][lane] = a3;
    }
    if (lane == 0) sDs[wave] = dsum;   // dsum is lane-uniform: store, do NOT reduce
    __syncthreads();
    if (wave >= 4) {
        int w = wave - 4;
        float4 q;
        q = sAcc[0][w][lane]; q.x += a0.x; q.y += a0.y; q.z += a0.z; q.w += a0.w; sAcc[0][w][lane] = q;
        q = sAcc[1][w][lane]; q.x += a1.x; q.y += a1.y; q.z += a1.z; q.w += a1.w; sAcc[1][w][lane] = q;
        q = sAcc[2][w][lane]; q.x += a2.x; q.y += a2.y; q.z += a2.z; q.w += a2.w; sAcc[2][w][lane] = q;
        q = sAcc[3][w][lane]; q.x += a3.x; q.y += a3.y; q.z += a3.z; q.w += a3.w; sAcc[3][w][lane] = q;
    }
    __syncthreads();

    // Epilogue: wave h (h<4) reduces head h across the 4 merged partials + 8 denoms
    if (wave < NHEAD) {
        float4 q0 = sAcc[wave][0][lane], q1 = sAcc[wave][1][lane],
               q2 = sAcc[wave][2][lane], q3 = sAcc[wave][3][lane];
        float4 acc = make_float4((q0.x + q1.x) + (q2.x + q3.x),
                                 (q0.y + q1.y) + (q2.y + q3.y),
                                 (q0.z + q1.z) + (q2.z + q3.z),
                                 (q0.w + q1.w) + (q2.w + q3.w));
        float4 d0 = sDs[0], d1 = sDs[1], d2 = sDs[2], d3 = sDs[3];
        float4 d4 = sDs[4], d5 = sDs[5], d6 = sDs[6], d7 = sDs[7];
        float4 dt = make_float4(((d0.x + d1.x) + (d2.x + d3.x)) + ((d4.x + d5.x) + (d6.x + d7.x)),
                                ((d0.y + d1.y) + (d2.y + d3.y)) + ((d4.y + d5.y) + (d6.y + d7.y)),
                                ((d0.z + d1.z) + (d2.z + d3.z)) + ((d4.z + d5.z) + (d6.z + d7.z)),
                                ((d0.w + d1.w) + (d2.w + d3.w)) + ((d4.w + d5.w) + (d6.w + d7.w)));
        float dh = (wave == 0) ? dt.x : (wave == 1) ? dt.y : (wave == 2) ? dt.z : dt.w;
        float inv = 1.0f / dh;
        ((float4*)o)[wave * 64 + lane] =
            make_float4(acc.x * inv, acc.y * inv, acc.z * inv, acc.w * inv);
    }
}

extern "C" void kernel_launch(void* const* d_in, const int* in_sizes, int n_in,
                              void* d_out, int out_size, void* d_ws, size_t ws_size,
                              hipStream_t stream) {
    const float* ch    = (const float*)d_in[0];
    const float* W_lin = (const float*)d_in[1];
    const float* b_lin = (const float*)d_in[2];
    const float* W_att = (const float*)d_in[3];
    const float* b_att = (const float*)d_in[4];
    const int*   y     = (const int*)d_in[5];
    float* out = (float*)d_out;
    float* ws  = (float*)d_ws;  // ~4.2 MB used

    k_prep  <<<NHEAD + 63, 256, 0, stream>>>(W_lin, b_lin, W_att, b_att, ws);
    k_bucket<<<(N_ROWS + 255) / 256, 256, 0, stream>>>(y, ws);
    k_pool  <<<NCLS, 512, 0, stream>>>(ch, out, ws);
}